// Round 6
// baseline (112.584 us; speedup 1.0000x reference)
//
#include <hip/hip_runtime.h>
#include <cmath>

// Problem constants (fixed by the reference)
#define BB   64
#define TT   4096
#define DD1  256
#define DD2  128
#define UU   64
#define NT   32      // T tiles per batch row
#define TTILE 128    // rows per block
#define CH   32      // rows per chunk (staged in LDS)
#define THREADS 256

// A rows are 264 bf16 (=528 B): row-to-row bank rotation, 16B-aligned.
#define ROWB 528
#define HL   16896   // byte delta hi-array -> lo-array (32*528)

// LDS byte offsets (static shared, 36.5 KB -> 2 blocks/CU)
#define AH_OFF   0        // A hi [32][264] bf16 = 16896 B
#define AL_OFF   16896    // A lo
#define BIAS_OFF 33792    // 64 f32
#define WCH_OFF  34048    // 32 f32 softmax weights
#define LOGP_OFF 34176    // 64 f32 logit partials (2 u-halves x 32 rows)
#define ML_OFF   34432    // [0]=m [1]=l [2]=rescale [3]=pad
#define RED_OFF  34448    // 512 f32 (bias partials)
#define LDS_BYTES 36496

typedef short bf16x8 __attribute__((ext_vector_type(8)));
typedef float f32x4  __attribute__((ext_vector_type(4)));

__device__ __forceinline__ float tanh_fast(float x) {
    float ax = fabsf(x);
    float e  = __expf(-2.0f * ax);
    float t  = __fdividef(1.0f - e, 1.0f + e);
    return x < 0.0f ? -t : t;
}

// 8 f32 -> bf16 hi (truncate) + bf16 lo (residual, truncated)
__device__ __forceinline__ void cvt_hilo(float4 f0, float4 f1, bf16x8& h8, bf16x8& l8) {
    float x[8] = {f0.x, f0.y, f0.z, f0.w, f1.x, f1.y, f1.z, f1.w};
    union { unsigned u[4]; bf16x8 v; } H, L;
    #pragma unroll
    for (int p = 0; p < 4; ++p) {
        unsigned a = __float_as_uint(x[2*p]), b = __float_as_uint(x[2*p+1]);
        H.u[p] = (a >> 16) | (b & 0xffff0000u);
        float d0 = x[2*p]   - __uint_as_float(a & 0xffff0000u);
        float d1 = x[2*p+1] - __uint_as_float(b & 0xffff0000u);
        L.u[p] = (__float_as_uint(d0) >> 16) | (__float_as_uint(d1) & 0xffff0000u);
    }
    h8 = H.v; l8 = L.v;
}

// W1 column u, k = kb..kb+7 -> hi/lo bf16x8 B-frag (stride UU floats)
__device__ __forceinline__ void load_bfrag(const float* __restrict__ W1, int kb, int u,
                                           bf16x8& bh, bf16x8& bl) {
    float4 x0, x1;
    x0.x = W1[(kb + 0) * UU + u]; x0.y = W1[(kb + 1) * UU + u];
    x0.z = W1[(kb + 2) * UU + u]; x0.w = W1[(kb + 3) * UU + u];
    x1.x = W1[(kb + 4) * UU + u]; x1.y = W1[(kb + 5) * UU + u];
    x1.z = W1[(kb + 6) * UU + u]; x1.w = W1[(kb + 7) * UU + u];
    cvt_hilo(x0, x1, bh, bl);
}

// Stage layout: thread covers, for j=0..3, row (8j+s), dims [8*q31, 8*q31+8)
// (pf[2j], pf[2j+1] = two consecutive float4 of that row).
#define STAGE_LOAD(pf, gptr) { \
    const float4* g_ = (const float4*)(gptr); \
    _Pragma("unroll") \
    for (int j_ = 0; j_ < 4; ++j_) { \
        pf[2*j_]   = g_[j_*512 + 2*tid]; \
        pf[2*j_+1] = g_[j_*512 + 2*tid + 1]; } }

#define STAGE_WRITE(pf) { \
    _Pragma("unroll") \
    for (int j_ = 0; j_ < 4; ++j_) { \
        bf16x8 h8_, l8_; \
        cvt_hilo(pf[2*j_], pf[2*j_+1], h8_, l8_); \
        char* p_ = smem + (8*j_ + s) * ROWB + 16*q31; \
        *(bf16x8*)(p_ + AH_OFF) = h8_; \
        *(bf16x8*)(p_ + AL_OFF) = l8_; } }

// One chunk iteration. pfCur holds chunk cc (also in LDS A). If DO_NEXT,
// pfNxt receives chunk cc+1 (issued at top, LDS-written at bottom).
#define ITER(pfCur, pfNxt, cc, DO_NEXT) { \
    if (DO_NEXT) { STAGE_LOAD(pfNxt, seqbase + (size_t)((cc)+1) * CH * DD1); } \
    f32x4 acc0 = {0.f,0.f,0.f,0.f}, acc1 = {0.f,0.f,0.f,0.f}; \
    _Pragma("unroll") \
    for (int ks = 0; ks < 8; ++ks) { \
        const int off_ = ks * 64; \
        bf16x8 ah_ = *(const bf16x8*)(smem + aB + off_); \
        bf16x8 al_ = *(const bf16x8*)(smem + aB + HL + off_); \
        acc0 = __builtin_amdgcn_mfma_f32_16x16x32_bf16(ah_, b0h[ks], acc0, 0, 0, 0); \
        acc1 = __builtin_amdgcn_mfma_f32_16x16x32_bf16(ah_, b1h[ks], acc1, 0, 0, 0); \
        acc0 = __builtin_amdgcn_mfma_f32_16x16x32_bf16(ah_, b0l[ks], acc0, 0, 0, 0); \
        acc1 = __builtin_amdgcn_mfma_f32_16x16x32_bf16(ah_, b1l[ks], acc1, 0, 0, 0); \
        acc0 = __builtin_amdgcn_mfma_f32_16x16x32_bf16(al_, b0h[ks], acc0, 0, 0, 0); \
        acc1 = __builtin_amdgcn_mfma_f32_16x16x32_bf16(al_, b1h[ks], acc1, 0, 0, 0); \
    } \
    float lp_[4]; \
    _Pragma("unroll") \
    for (int r_ = 0; r_ < 4; ++r_) { \
        float e0_ = tanh_fast(acc0[r_] + bias0); \
        float e1_ = tanh_fast(acc1[r_] + bias1); \
        float p_  = e0_ * w20 + e1_ * w21; \
        p_ += __shfl_xor(p_, 1, 64); \
        p_ += __shfl_xor(p_, 2, 64); \
        p_ += __shfl_xor(p_, 4, 64); \
        p_ += __shfl_xor(p_, 8, 64); \
        lp_[r_] = p_; \
    } \
    if (l15 == 0) { \
        _Pragma("unroll") \
        for (int r_ = 0; r_ < 4; ++r_) flogp[nh * 32 + 16 * mf + kg * 4 + r_] = lp_[r_]; \
    } \
    __syncthreads();                        /* (A) logits visible */ \
    if (tid < 32) { \
        float lg_ = flogp[tid] + flogp[32 + tid]; \
        float mx_ = lg_; \
        mx_ = fmaxf(mx_, __shfl_xor(mx_, 1, 64)); \
        mx_ = fmaxf(mx_, __shfl_xor(mx_, 2, 64)); \
        mx_ = fmaxf(mx_, __shfl_xor(mx_, 4, 64)); \
        mx_ = fmaxf(mx_, __shfl_xor(mx_, 8, 64)); \
        mx_ = fmaxf(mx_, __shfl_xor(mx_, 16, 64)); \
        float mold_ = fml[0]; \
        float mnew_ = fmaxf(mold_, mx_); \
        float rsc_  = __expf(mold_ - mnew_);   /* first chunk: exp(-inf)=0 */ \
        float wv_   = __expf(lg_ - mnew_); \
        float ss_   = wv_; \
        ss_ += __shfl_xor(ss_, 1, 64); \
        ss_ += __shfl_xor(ss_, 2, 64); \
        ss_ += __shfl_xor(ss_, 4, 64); \
        ss_ += __shfl_xor(ss_, 8, 64); \
        ss_ += __shfl_xor(ss_, 16, 64); \
        fwch[tid] = wv_; \
        if (tid == 0) { fml[0] = mnew_; fml[1] = fml[1] * rsc_ + ss_; fml[2] = rsc_; } \
    } \
    __syncthreads();                        /* (B) weights visible */ \
    { \
        float rsc_ = fml[2]; \
        accA.x *= rsc_; accA.y *= rsc_; accA.z *= rsc_; accA.w *= rsc_; \
        accB.x *= rsc_; accB.y *= rsc_; accB.z *= rsc_; accB.w *= rsc_; \
        _Pragma("unroll") \
        for (int j_ = 0; j_ < 4; ++j_) { \
            float wr_ = fwch[8 * j_ + s]; \
            accA.x = fmaf(wr_, pfCur[2*j_].x, accA.x); \
            accA.y = fmaf(wr_, pfCur[2*j_].y, accA.y); \
            accA.z = fmaf(wr_, pfCur[2*j_].z, accA.z); \
            accA.w = fmaf(wr_, pfCur[2*j_].w, accA.w); \
            accB.x = fmaf(wr_, pfCur[2*j_+1].x, accB.x); \
            accB.y = fmaf(wr_, pfCur[2*j_+1].y, accB.y); \
            accB.z = fmaf(wr_, pfCur[2*j_+1].z, accB.z); \
            accB.w = fmaf(wr_, pfCur[2*j_+1].w, accB.w); \
        } \
    } \
    if (DO_NEXT) { STAGE_WRITE(pfNxt); __syncthreads(); }  /* (C) next chunk in LDS */ }

__global__ __launch_bounds__(THREADS, 2)   // 2 blocks/CU, VGPR cap 256
void caa_main(const float* __restrict__ seq, const float* __restrict__ ctx,
              const float* __restrict__ W1, const float* __restrict__ W2,
              float* __restrict__ part) {
    __shared__ __align__(16) char smem[LDS_BYTES];
    float* fml   = (float*)(smem + ML_OFF);
    float* fbias = (float*)(smem + BIAS_OFF);
    float* fwch  = (float*)(smem + WCH_OFF);
    float* flogp = (float*)(smem + LOGP_OFF);
    float* fred  = (float*)(smem + RED_OFF);

    const int tid = threadIdx.x;
    const int bx  = blockIdx.x;
    const int b    = bx >> 5, tile = bx & 31;
    const int w    = tid >> 6, l = tid & 63;
    const int l15  = l & 15,  kg = l >> 4;     // MFMA input: row/col = l15, k-octet = kg
    const int mf   = w & 1,   nh = w >> 1;     // wave -> m-frag (16 rows), u-half (32 u)
    const int s    = tid >> 5, q31 = tid & 31; // staging: row-slot s, dim-slot q31

    const float* seqbase = seq + ((size_t)b * TT + (size_t)tile * TTILE) * DD1;

    // ---- chunk 0 prefetch into registers ----
    float4 pfX[8], pfY[8];
    STAGE_LOAD(pfX, seqbase);

    // ---- B-frags (W1_seq) resident in registers: 2 u-groups x 8 ks x hi/lo ----
    const int u0g = nh * 32 + l15, u1g = u0g + 16;
    bf16x8 b0h[8], b0l[8], b1h[8], b1l[8];
    #pragma unroll
    for (int ks = 0; ks < 8; ++ks) {
        int kb = ks * 32 + kg * 8;
        load_bfrag(W1, kb, u0g, b0h[ks], b0l[ks]);
        load_bfrag(W1, kb, u1g, b1h[ks], b1l[ks]);
    }

    // ---- bias partials: 4 c-chunks x 64 u ----
    {
        int cq = tid >> 6;
        float sacc = 0.f;
        const float* cb = ctx + b * DD2 + cq * 32;
        const float* wb = W1 + (size_t)(DD1 + cq * 32) * UU + l;
        #pragma unroll
        for (int c = 0; c < 32; ++c) sacc = fmaf(cb[c], wb[c * UU], sacc);
        fred[cq * 64 + l] = sacc;
    }
    if (tid == 0) { fml[0] = -INFINITY; fml[1] = 0.f; }
    __syncthreads();
    if (tid < 64) {
        fbias[tid] = fred[tid] + fred[64 + tid] + fred[128 + tid] + fred[192 + tid];
    }
    STAGE_WRITE(pfX);          // chunk 0 -> LDS (compiler waits the loads)
    __syncthreads();

    const float bias0 = fbias[u0g], bias1 = fbias[u1g];
    const float w20 = W2[u0g], w21 = W2[u1g];
    const int aB = AH_OFF + (16 * mf + l15) * ROWB + kg * 16;

    float4 accA = make_float4(0.f,0.f,0.f,0.f);   // dims 8*q31..+3, rows s mod 8
    float4 accB = make_float4(0.f,0.f,0.f,0.f);   // dims 8*q31+4..+7

    ITER(pfX, pfY, 0, 1)
    ITER(pfY, pfX, 1, 1)
    ITER(pfX, pfY, 2, 1)
    ITER(pfY, pfX, 3, 0)

    // ---- cross-thread reduce over s (8 row-slots), reusing dead A region ----
    __syncthreads();
    float* pr = (float*)smem;                  // [s][264] f32, 8448 B
    {
        const int d0 = 8 * q31;
        pr[264*s + d0 + 0] = accA.x; pr[264*s + d0 + 1] = accA.y;
        pr[264*s + d0 + 2] = accA.z; pr[264*s + d0 + 3] = accA.w;
        pr[264*s + d0 + 4] = accB.x; pr[264*s + d0 + 5] = accB.y;
        pr[264*s + d0 + 6] = accB.z; pr[264*s + d0 + 7] = accB.w;
    }
    __syncthreads();
    {
        float v = 0.f;
        #pragma unroll
        for (int s2 = 0; s2 < 8; ++s2) v += pr[264*s2 + tid];
        size_t base = (size_t)bx * 258;
        part[base + tid] = v;
        if (tid == 0) part[base + 256] = fml[0];
        if (tid == 1) part[base + 257] = fml[1];
    }
}

__global__ __launch_bounds__(256)
void caa_combine(const float* __restrict__ part, float* __restrict__ out) {
    const int b = blockIdx.x, tid = threadIdx.x;
    __shared__ float sm[NT], sl[NT];
    if (tid < NT) {
        sm[tid] = part[(size_t)(b * NT + tid) * 258 + 256];
        sl[tid] = part[(size_t)(b * NT + tid) * 258 + 257];
    }
    __syncthreads();
    float M = sm[0];
    #pragma unroll
    for (int i = 1; i < NT; ++i) M = fmaxf(M, sm[i]);
    float S = 0.0f, o = 0.0f;
    #pragma unroll
    for (int i = 0; i < NT; ++i) {
        float e = __expf(sm[i] - M);
        S = fmaf(sl[i], e, S);
        o = fmaf(e, part[(size_t)(b * NT + i) * 258 + tid], o);
    }
    out[b * 256 + tid] = __fdividef(o, S);
}

extern "C" void kernel_launch(void* const* d_in, const int* in_sizes, int n_in,
                              void* d_out, int out_size, void* d_ws, size_t ws_size,
                              hipStream_t stream) {
    const float* seq = (const float*)d_in[0];
    const float* ctx = (const float*)d_in[1];
    const float* W1  = (const float*)d_in[2];
    const float* W2  = (const float*)d_in[3];
    float* part = (float*)d_ws;   // BB*NT*258*4 = 2,113,536 B of scratch

    caa_main<<<dim3(BB * NT), dim3(THREADS), 0, stream>>>(seq, ctx, W1, W2, part);
    caa_combine<<<dim3(BB), dim3(256), 0, stream>>>(part, (float*)d_out);
}

// Round 7
// 65.655 us; speedup vs baseline: 1.7148x; 1.7148x over previous
//
#include <hip/hip_runtime.h>
#include <cmath>

// Problem constants (fixed by the reference)
#define BB   64
#define TT   4096
#define DD1  256
#define DD2  128
#define UU   64
#define NT   16      // T tiles per batch row
#define TTILE 256    // rows per block
#define CH   32      // rows per chunk (staged in LDS)
#define NCH  8
#define THREADS 256

// A rows: 264 fp16 (=528 B): 256 data + 8 pad -> 4-dword bank rotation/row.
#define ROWB 528

// LDS byte offsets (static shared, 35.5 KB -> 3 blocks/CU at (256,3))
#define A0_OFF   0        // A buf0 [32][264] fp16 = 16896 B
#define A1_OFF   16896    // A buf1
#define BIAS_OFF 33792    // 64 f32
#define WCH_OFF  34048    // 32 f32 softmax weights
#define LOGP_OFF 34176    // 64 f32 logit partials (2 u-halves x 32 rows)
#define ML_OFF   34432    // [0]=m [1]=l [2]=rescale [3]=pad
#define RED_OFF  34448    // 256 f32 (bias partials)
#define LDS_BYTES 35472

typedef _Float16 fp16x8 __attribute__((ext_vector_type(8)));
typedef float    f32x4  __attribute__((ext_vector_type(4)));

__device__ __forceinline__ float tanh_fast(float x) {
    float ax = fabsf(x);
    float e  = __expf(-2.0f * ax);
    float t  = __fdividef(1.0f - e, 1.0f + e);
    return x < 0.0f ? -t : t;
}

// 8 f32 -> fp16x8 (RNE per element)
__device__ __forceinline__ fp16x8 cvt8(float4 a, float4 b) {
    fp16x8 v;
    v[0] = (_Float16)a.x; v[1] = (_Float16)a.y; v[2] = (_Float16)a.z; v[3] = (_Float16)a.w;
    v[4] = (_Float16)b.x; v[5] = (_Float16)b.y; v[6] = (_Float16)b.z; v[7] = (_Float16)b.w;
    return v;
}

__global__ __launch_bounds__(THREADS, 3)   // 3 waves/EU -> 3 blocks/CU, VGPR cap ~170
void caa_main(const float* __restrict__ seq, const float* __restrict__ ctx,
              const float* __restrict__ W1, const float* __restrict__ W2,
              float* __restrict__ part) {
    __shared__ __align__(16) char smem[LDS_BYTES];
    float* fml   = (float*)(smem + ML_OFF);
    float* fbias = (float*)(smem + BIAS_OFF);
    float* fwch  = (float*)(smem + WCH_OFF);
    float* flogp = (float*)(smem + LOGP_OFF);
    float* fred  = (float*)(smem + RED_OFF);

    const int tid = threadIdx.x;
    const int bx  = blockIdx.x;
    const int b    = bx >> 4, tile = bx & 15;
    const int w    = tid >> 6, l = tid & 63;
    const int l15  = l & 15,  kg = l >> 4;     // MFMA input: row/col = l15, k-octet = kg
    const int mf   = w & 1,   nh = w >> 1;     // wave -> m-frag (16 rows), u-half (32 u)
    const int s    = tid >> 5, q31 = tid & 31; // staging: row-slot s, dim-octet q31
    const int dq   = tid & 63, to = tid >> 6;  // accum: dim-quad dq, row-octet to (== w)

    const float* seqbase = seq + ((size_t)b * TT + (size_t)tile * TTILE) * DD1;

    // ---- chunk 0 global prefetch (8 float4 = 32 VGPR) ----
    // float4 idx f = j*512 + 2tid(+1) -> row 8j+s, floats 8q31..+7
    float4 pf[8];
    {
        const float4* g = (const float4*)seqbase;
        #pragma unroll
        for (int j = 0; j < 4; ++j) {
            pf[2*j]   = g[j*512 + 2*tid];
            pf[2*j+1] = g[j*512 + 2*tid + 1];
        }
    }

    // ---- B-frags (W1_seq, fp16): 2 u-groups x 8 ks, 64 VGPR ----
    const int u0g = nh * 32 + l15, u1g = u0g + 16;
    fp16x8 b0h[8], b1h[8];
    #pragma unroll
    for (int ks = 0; ks < 8; ++ks) {
        const int kb = ks * 32 + kg * 8;
        float4 x0, x1;
        x0.x = W1[(kb+0)*UU + u0g]; x0.y = W1[(kb+1)*UU + u0g];
        x0.z = W1[(kb+2)*UU + u0g]; x0.w = W1[(kb+3)*UU + u0g];
        x1.x = W1[(kb+4)*UU + u0g]; x1.y = W1[(kb+5)*UU + u0g];
        x1.z = W1[(kb+6)*UU + u0g]; x1.w = W1[(kb+7)*UU + u0g];
        b0h[ks] = cvt8(x0, x1);
        x0.x = W1[(kb+0)*UU + u1g]; x0.y = W1[(kb+1)*UU + u1g];
        x0.z = W1[(kb+2)*UU + u1g]; x0.w = W1[(kb+3)*UU + u1g];
        x1.x = W1[(kb+4)*UU + u1g]; x1.y = W1[(kb+5)*UU + u1g];
        x1.z = W1[(kb+6)*UU + u1g]; x1.w = W1[(kb+7)*UU + u1g];
        b1h[ks] = cvt8(x0, x1);
    }

    // ---- bias partials: 4 c-chunks x 64 u ----
    {
        const int cq = tid >> 6;
        float sacc = 0.f;
        const float* cb = ctx + b * DD2 + cq * 32;
        const float* wb = W1 + (size_t)(DD1 + cq * 32) * UU + l;
        #pragma unroll
        for (int c = 0; c < 32; ++c) sacc = fmaf(cb[c], wb[c * UU], sacc);
        fred[cq * 64 + l] = sacc;
    }
    if (tid == 0) { fml[0] = -INFINITY; fml[1] = 0.f; }
    __syncthreads();
    if (tid < 64) {
        fbias[tid] = fred[tid] + fred[64 + tid] + fred[128 + tid] + fred[192 + tid];
    }
    // ---- chunk 0 -> A0 (fp16, b128 writes; compiler waits pf loads) ----
    #pragma unroll
    for (int j = 0; j < 4; ++j)
        *(fp16x8*)(smem + A0_OFF + (8*j + s) * ROWB + q31 * 16) = cvt8(pf[2*j], pf[2*j+1]);
    __syncthreads();

    const float bias0 = fbias[u0g], bias1 = fbias[u1g];
    const float w20 = W2[u0g], w21 = W2[u1g];
    const int aB = (16 * mf + l15) * ROWB + kg * 16;   // A-frag byte base within buffer

    float4 accA = make_float4(0.f, 0.f, 0.f, 0.f);     // dims 4dq..+3, rows to*8..+7 partial

    for (int c = 0; c < NCH; ++c) {
        const char* bufc = smem + ((c & 1) ? A1_OFF : A0_OFF);
        char*       bufn = smem + ((c & 1) ? A0_OFF : A1_OFF);
        // issue next-chunk loads; consumed at STAGE_WRITE after barrier (B)
        if (c < NCH - 1) {
            const float4* g = (const float4*)(seqbase + (size_t)(c + 1) * CH * DD1);
            #pragma unroll
            for (int j = 0; j < 4; ++j) {
                pf[2*j]   = g[j*512 + 2*tid];
                pf[2*j+1] = g[j*512 + 2*tid + 1];
            }
        }
        // ---- fp16 MFMA GEMM: 32x64 tile, K=256, 16 MFMA/wave ----
        f32x4 acc0 = {0.f,0.f,0.f,0.f}, acc1 = {0.f,0.f,0.f,0.f};
        #pragma unroll
        for (int ks = 0; ks < 8; ++ks) {
            fp16x8 ah = *(const fp16x8*)(bufc + aB + ks * 64);
            acc0 = __builtin_amdgcn_mfma_f32_16x16x32_f16(ah, b0h[ks], acc0, 0, 0, 0);
            acc1 = __builtin_amdgcn_mfma_f32_16x16x32_f16(ah, b1h[ks], acc1, 0, 0, 0);
        }
        // ---- epilogue: tanh + W2 dot; reduce over u (lane&15) ----
        float lp[4];
        #pragma unroll
        for (int r = 0; r < 4; ++r) {
            float e0 = tanh_fast(acc0[r] + bias0);
            float e1 = tanh_fast(acc1[r] + bias1);
            float p  = e0 * w20 + e1 * w21;
            p += __shfl_xor(p, 1, 64);
            p += __shfl_xor(p, 2, 64);
            p += __shfl_xor(p, 4, 64);
            p += __shfl_xor(p, 8, 64);
            lp[r] = p;
        }
        if (l15 == 0) {      // C/D row = kg*4 + r within m-frag (verified layout)
            #pragma unroll
            for (int r = 0; r < 4; ++r) flogp[nh * 32 + 16 * mf + kg * 4 + r] = lp[r];
        }
        __syncthreads();                        // (A) logits visible
        // ---- online softmax over 32 chunk rows ----
        if (tid < 32) {
            float lg = flogp[tid] + flogp[32 + tid];
            float mx = lg;
            mx = fmaxf(mx, __shfl_xor(mx, 1, 64));
            mx = fmaxf(mx, __shfl_xor(mx, 2, 64));
            mx = fmaxf(mx, __shfl_xor(mx, 4, 64));
            mx = fmaxf(mx, __shfl_xor(mx, 8, 64));
            mx = fmaxf(mx, __shfl_xor(mx, 16, 64));
            float mold = fml[0];
            float mnew = fmaxf(mold, mx);
            float rsc  = __expf(mold - mnew);   // first chunk: exp(-inf)=0
            float wv   = __expf(lg - mnew);
            float ss   = wv;
            ss += __shfl_xor(ss, 1, 64);
            ss += __shfl_xor(ss, 2, 64);
            ss += __shfl_xor(ss, 4, 64);
            ss += __shfl_xor(ss, 8, 64);
            ss += __shfl_xor(ss, 16, 64);
            fwch[tid] = wv;
            if (tid == 0) { fml[0] = mnew; fml[1] = fml[1] * rsc + ss; fml[2] = rsc; }
        }
        __syncthreads();                        // (B) weights visible
        // ---- stage next chunk into the OTHER buffer (no reader conflict) ----
        if (c < NCH - 1) {
            #pragma unroll
            for (int j = 0; j < 4; ++j)
                *(fp16x8*)(bufn + (8*j + s) * ROWB + q31 * 16) = cvt8(pf[2*j], pf[2*j+1]);
        }
        // ---- weighted accumulation from current fp16 tile ----
        {
            float rsc = fml[2];
            accA.x *= rsc; accA.y *= rsc; accA.z *= rsc; accA.w *= rsc;
            #pragma unroll
            for (int i = 0; i < 8; ++i) {
                const int row = to * 8 + i;
                float wr = fwch[row];
                union { uint2 u; _Float16 h[4]; } v;
                v.u = *(const uint2*)(bufc + row * ROWB + dq * 8);
                accA.x = fmaf(wr, (float)v.h[0], accA.x);
                accA.y = fmaf(wr, (float)v.h[1], accA.y);
                accA.z = fmaf(wr, (float)v.h[2], accA.z);
                accA.w = fmaf(wr, (float)v.h[3], accA.w);
            }
        }
        __syncthreads();                        // (C) next tile staged, iteration done
    }

    // ---- cross-wave reduce over 'to' (4 row-octets), reusing dead A0 region ----
    float* pr = (float*)(smem + A0_OFF);       // [to][256] f32 = 4 KB
    {
        const int d0 = 4 * dq;
        pr[256*to + d0 + 0] = accA.x; pr[256*to + d0 + 1] = accA.y;
        pr[256*to + d0 + 2] = accA.z; pr[256*to + d0 + 3] = accA.w;
    }
    __syncthreads();
    {
        float v = pr[tid] + pr[256 + tid] + pr[512 + tid] + pr[768 + tid];
        size_t base = (size_t)bx * 258;
        part[base + tid] = v;
        if (tid == 0) part[base + 256] = fml[0];
        if (tid == 1) part[base + 257] = fml[1];
    }
}

__global__ __launch_bounds__(256)
void caa_combine(const float* __restrict__ part, float* __restrict__ out) {
    const int b = blockIdx.x, tid = threadIdx.x;
    __shared__ float sm[NT], sl[NT];
    if (tid < NT) {
        sm[tid] = part[(size_t)(b * NT + tid) * 258 + 256];
        sl[tid] = part[(size_t)(b * NT + tid) * 258 + 257];
    }
    __syncthreads();
    float M = sm[0];
    #pragma unroll
    for (int i = 1; i < NT; ++i) M = fmaxf(M, sm[i]);
    float S = 0.0f, o = 0.0f;
    #pragma unroll
    for (int i = 0; i < NT; ++i) {
        float e = __expf(sm[i] - M);
        S = fmaf(sl[i], e, S);
        o = fmaf(e, part[(size_t)(b * NT + i) * 258 + tid], o);
    }
    out[b * 256 + tid] = __fdividef(o, S);
}

extern "C" void kernel_launch(void* const* d_in, const int* in_sizes, int n_in,
                              void* d_out, int out_size, void* d_ws, size_t ws_size,
                              hipStream_t stream) {
    const float* seq = (const float*)d_in[0];
    const float* ctx = (const float*)d_in[1];
    const float* W1  = (const float*)d_in[2];
    const float* W2  = (const float*)d_in[3];
    float* part = (float*)d_ws;   // BB*NT*258*4 = 1,056,768 B of scratch

    caa_main<<<dim3(BB * NT), dim3(THREADS), 0, stream>>>(seq, ctx, W1, W2, part);
    caa_combine<<<dim3(BB), dim3(256), 0, stream>>>(part, (float*)d_out);
}

// Round 8
// 52.557 us; speedup vs baseline: 2.1421x; 1.2492x over previous
//
#include <hip/hip_runtime.h>
#include <cmath>

// Problem constants (fixed by the reference)
#define BB   64
#define TT   4096
#define DD1  256
#define DD2  128
#define UU   64
#define NT   16      // T tiles per batch row
#define TTILE 256    // rows per block
#define CH   32      // rows per chunk (staged in LDS)
#define NCH  8
#define THREADS 256

// A rows: 264 fp16 (=528 B): 256 data + 8 pad -> 4-dword bank rotation/row.
#define ROWB 528

// LDS byte offsets (static shared, 35.7 KB -> 4 blocks/CU at (256,4))
#define A0_OFF   0        // A buf0 [32][264] fp16 = 16896 B
#define A1_OFF   16896    // A buf1
#define BIAS_OFF 33792    // 64 f32
#define WCH_OFF  34048    // 32 f32 softmax weights
#define LOGP_OFF 34176    // 128 f32 logit partials (4 u-groups x 32 rows)
#define ML_OFF   34688    // [0]=m [1]=l [2]=rescale [3]=pad
#define RED_OFF  34704    // 256 f32 (bias partials)
#define LDS_BYTES 35728

typedef _Float16 fp16x8 __attribute__((ext_vector_type(8)));
typedef float    f32x4  __attribute__((ext_vector_type(4)));

__device__ __forceinline__ float tanh_fast(float x) {
    float ax = fabsf(x);
    float e  = __expf(-2.0f * ax);
    float t  = __fdividef(1.0f - e, 1.0f + e);
    return x < 0.0f ? -t : t;
}

// 8 f32 -> fp16x8 (RNE per element)
__device__ __forceinline__ fp16x8 cvt8(float4 a, float4 b) {
    fp16x8 v;
    v[0] = (_Float16)a.x; v[1] = (_Float16)a.y; v[2] = (_Float16)a.z; v[3] = (_Float16)a.w;
    v[4] = (_Float16)b.x; v[5] = (_Float16)b.y; v[6] = (_Float16)b.z; v[7] = (_Float16)b.w;
    return v;
}

__global__ __launch_bounds__(THREADS, 4)   // 4 waves/EU -> 4 blocks/CU, VGPR cap 128
void caa_main(const float* __restrict__ seq, const float* __restrict__ ctx,
              const float* __restrict__ W1, const float* __restrict__ W2,
              float* __restrict__ part) {
    __shared__ __align__(16) char smem[LDS_BYTES];
    float* fml   = (float*)(smem + ML_OFF);
    float* fbias = (float*)(smem + BIAS_OFF);
    float* fwch  = (float*)(smem + WCH_OFF);
    float* flogp = (float*)(smem + LOGP_OFF);
    float* fred  = (float*)(smem + RED_OFF);

    const int tid = threadIdx.x;
    const int bx  = blockIdx.x;
    const int b    = bx >> 4, tile = bx & 15;
    const int w    = tid >> 6, l = tid & 63;
    const int l15  = l & 15,  kg = l >> 4;     // MFMA input: row/col = l15, k-octet = kg
    const int s    = tid >> 5, q31 = tid & 31; // staging: row-slot s, dim-octet q31
    const int dq   = tid & 63, to = tid >> 6;  // accum: dim-quad dq, row-octet to (== w)

    const float* seqbase = seq + ((size_t)b * TT + (size_t)tile * TTILE) * DD1;

    // ---- chunk 0 global prefetch (8 float4 = 32 VGPR) ----
    // float4 idx f = j*512 + 2tid(+1) -> row 8j+s, floats 8q31..+7
    float4 pf[8];
    {
        const float4* g = (const float4*)seqbase;
        #pragma unroll
        for (int j = 0; j < 4; ++j) {
            pf[2*j]   = g[j*512 + 2*tid];
            pf[2*j+1] = g[j*512 + 2*tid + 1];
        }
    }

    // ---- B-frags (W1_seq, fp16): 1 u-group of 16 per wave, 32 VGPR ----
    const int u0g = w * 16 + l15;
    fp16x8 bf[8];
    #pragma unroll
    for (int ks = 0; ks < 8; ++ks) {
        const int kb = ks * 32 + kg * 8;
        float4 x0, x1;
        x0.x = W1[(kb+0)*UU + u0g]; x0.y = W1[(kb+1)*UU + u0g];
        x0.z = W1[(kb+2)*UU + u0g]; x0.w = W1[(kb+3)*UU + u0g];
        x1.x = W1[(kb+4)*UU + u0g]; x1.y = W1[(kb+5)*UU + u0g];
        x1.z = W1[(kb+6)*UU + u0g]; x1.w = W1[(kb+7)*UU + u0g];
        bf[ks] = cvt8(x0, x1);
    }

    // ---- bias partials: 4 c-chunks x 64 u ----
    {
        const int cq = tid >> 6;
        float sacc = 0.f;
        const float* cb = ctx + b * DD2 + cq * 32;
        const float* wb = W1 + (size_t)(DD1 + cq * 32) * UU + l;
        #pragma unroll
        for (int c = 0; c < 32; ++c) sacc = fmaf(cb[c], wb[c * UU], sacc);
        fred[cq * 64 + l] = sacc;
    }
    if (tid == 0) { fml[0] = -INFINITY; fml[1] = 0.f; }
    __syncthreads();
    if (tid < 64) {
        fbias[tid] = fred[tid] + fred[64 + tid] + fred[128 + tid] + fred[192 + tid];
    }
    // ---- chunk 0 -> A0 (fp16, b128 writes; compiler waits pf loads) ----
    #pragma unroll
    for (int j = 0; j < 4; ++j)
        *(fp16x8*)(smem + A0_OFF + (8*j + s) * ROWB + q31 * 16) = cvt8(pf[2*j], pf[2*j+1]);
    __syncthreads();

    const float bias0 = fbias[u0g];
    const float w20   = W2[u0g];
    const int aB0 = (     l15) * ROWB + kg * 16;   // m-frag 0 A byte base
    const int aB1 = (16 + l15) * ROWB + kg * 16;   // m-frag 1

    float4 accA = make_float4(0.f, 0.f, 0.f, 0.f); // dims 4dq..+3, rows to*8..+7 partial

    for (int c = 0; c < NCH; ++c) {
        const char* bufc = smem + ((c & 1) ? A1_OFF : A0_OFF);
        char*       bufn = smem + ((c & 1) ? A0_OFF : A1_OFF);
        // issue next-chunk loads; consumed at stage-write after barrier (B)
        if (c < NCH - 1) {
            const float4* g = (const float4*)(seqbase + (size_t)(c + 1) * CH * DD1);
            #pragma unroll
            for (int j = 0; j < 4; ++j) {
                pf[2*j]   = g[j*512 + 2*tid];
                pf[2*j+1] = g[j*512 + 2*tid + 1];
            }
        }
        // ---- fp16 MFMA GEMM: 32 rows x 16 u per wave, K=256, 16 MFMA ----
        f32x4 acc0 = {0.f,0.f,0.f,0.f}, acc1 = {0.f,0.f,0.f,0.f};
        #pragma unroll
        for (int ks = 0; ks < 8; ++ks) {
            fp16x8 ah0 = *(const fp16x8*)(bufc + aB0 + ks * 64);
            fp16x8 ah1 = *(const fp16x8*)(bufc + aB1 + ks * 64);
            acc0 = __builtin_amdgcn_mfma_f32_16x16x32_f16(ah0, bf[ks], acc0, 0, 0, 0);
            acc1 = __builtin_amdgcn_mfma_f32_16x16x32_f16(ah1, bf[ks], acc1, 0, 0, 0);
        }
        // ---- epilogue: tanh + W2 dot; reduce over the 16 u lanes ----
        float lp0[4], lp1[4];
        #pragma unroll
        for (int r = 0; r < 4; ++r) {
            float p0 = tanh_fast(acc0[r] + bias0) * w20;
            float p1 = tanh_fast(acc1[r] + bias0) * w20;
            p0 += __shfl_xor(p0, 1, 64);
            p1 += __shfl_xor(p1, 1, 64);
            p0 += __shfl_xor(p0, 2, 64);
            p1 += __shfl_xor(p1, 2, 64);
            p0 += __shfl_xor(p0, 4, 64);
            p1 += __shfl_xor(p1, 4, 64);
            p0 += __shfl_xor(p0, 8, 64);
            p1 += __shfl_xor(p1, 8, 64);
            lp0[r] = p0; lp1[r] = p1;
        }
        if (l15 == 0) {      // C/D row = kg*4 + r within m-frag (verified layout)
            #pragma unroll
            for (int r = 0; r < 4; ++r) {
                flogp[w * 32 +      kg * 4 + r] = lp0[r];
                flogp[w * 32 + 16 + kg * 4 + r] = lp1[r];
            }
        }
        __syncthreads();                        // (A) logit partials visible
        // ---- online softmax over 32 chunk rows (sum 4 u-group partials) ----
        if (tid < 32) {
            float lg = flogp[tid] + flogp[32 + tid] + flogp[64 + tid] + flogp[96 + tid];
            float mx = lg;
            mx = fmaxf(mx, __shfl_xor(mx, 1, 64));
            mx = fmaxf(mx, __shfl_xor(mx, 2, 64));
            mx = fmaxf(mx, __shfl_xor(mx, 4, 64));
            mx = fmaxf(mx, __shfl_xor(mx, 8, 64));
            mx = fmaxf(mx, __shfl_xor(mx, 16, 64));
            float mold = fml[0];
            float mnew = fmaxf(mold, mx);
            float rsc  = __expf(mold - mnew);   // first chunk: exp(-inf)=0
            float wv   = __expf(lg - mnew);
            float ss   = wv;
            ss += __shfl_xor(ss, 1, 64);
            ss += __shfl_xor(ss, 2, 64);
            ss += __shfl_xor(ss, 4, 64);
            ss += __shfl_xor(ss, 8, 64);
            ss += __shfl_xor(ss, 16, 64);
            fwch[tid] = wv;
            if (tid == 0) { fml[0] = mnew; fml[1] = fml[1] * rsc + ss; fml[2] = rsc; }
        }
        __syncthreads();                        // (B) weights visible
        // ---- stage next chunk into the OTHER buffer ----
        if (c < NCH - 1) {
            #pragma unroll
            for (int j = 0; j < 4; ++j)
                *(fp16x8*)(bufn + (8*j + s) * ROWB + q31 * 16) = cvt8(pf[2*j], pf[2*j+1]);
        }
        // ---- weighted accumulation from current fp16 tile ----
        {
            float rsc = fml[2];
            accA.x *= rsc; accA.y *= rsc; accA.z *= rsc; accA.w *= rsc;
            #pragma unroll
            for (int i = 0; i < 8; ++i) {
                const int row = to * 8 + i;
                float wr = fwch[row];
                union { uint2 u; _Float16 h[4]; } v;
                v.u = *(const uint2*)(bufc + row * ROWB + dq * 8);
                accA.x = fmaf(wr, (float)v.h[0], accA.x);
                accA.y = fmaf(wr, (float)v.h[1], accA.y);
                accA.z = fmaf(wr, (float)v.h[2], accA.z);
                accA.w = fmaf(wr, (float)v.h[3], accA.w);
            }
        }
        __syncthreads();                        // (C) next tile staged, iteration done
    }

    // ---- cross-wave reduce over 'to' (4 row-octets), reusing dead A0 region ----
    float* pr = (float*)(smem + A0_OFF);       // [to][256] f32 = 4 KB
    {
        const int d0 = 4 * dq;
        pr[256*to + d0 + 0] = accA.x; pr[256*to + d0 + 1] = accA.y;
        pr[256*to + d0 + 2] = accA.z; pr[256*to + d0 + 3] = accA.w;
    }
    __syncthreads();
    {
        float v = pr[tid] + pr[256 + tid] + pr[512 + tid] + pr[768 + tid];
        size_t base = (size_t)bx * 258;
        part[base + tid] = v;
        if (tid == 0) part[base + 256] = fml[0];
        if (tid == 1) part[base + 257] = fml[1];
    }
}

__global__ __launch_bounds__(256)
void caa_combine(const float* __restrict__ part, float* __restrict__ out) {
    const int b = blockIdx.x, tid = threadIdx.x;
    __shared__ float sm[NT], sl[NT];
    if (tid < NT) {
        sm[tid] = part[(size_t)(b * NT + tid) * 258 + 256];
        sl[tid] = part[(size_t)(b * NT + tid) * 258 + 257];
    }
    __syncthreads();
    float M = sm[0];
    #pragma unroll
    for (int i = 1; i < NT; ++i) M = fmaxf(M, sm[i]);
    float S = 0.0f, o = 0.0f;
    #pragma unroll
    for (int i = 0; i < NT; ++i) {
        float e = __expf(sm[i] - M);
        S = fmaf(sl[i], e, S);
        o = fmaf(e, part[(size_t)(b * NT + i) * 258 + tid], o);
    }
    out[b * 256 + tid] = __fdividef(o, S);
}

extern "C" void kernel_launch(void* const* d_in, const int* in_sizes, int n_in,
                              void* d_out, int out_size, void* d_ws, size_t ws_size,
                              hipStream_t stream) {
    const float* seq = (const float*)d_in[0];
    const float* ctx = (const float*)d_in[1];
    const float* W1  = (const float*)d_in[2];
    const float* W2  = (const float*)d_in[3];
    float* part = (float*)d_ws;   // BB*NT*258*4 = 1,056,768 B of scratch

    caa_main<<<dim3(BB * NT), dim3(THREADS), 0, stream>>>(seq, ctx, W1, W2, part);
    caa_combine<<<dim3(BB), dim3(256), 0, stream>>>(part, (float*)d_out);
}